// Round 1
// baseline (358.637 us; speedup 1.0000x reference)
//
#include <hip/hip_runtime.h>
#include <hip/hip_bf16.h>
#include <math.h>

#define B_   16
#define N_   4096
#define S_   1024
#define C1_  128
#define C2_  256
#define CIN_ 384
#define CO_  128
#define ROWS (B_ * N_)   // 65536

typedef __attribute__((ext_vector_type(8))) __bf16 bf16x8;
typedef __attribute__((ext_vector_type(8))) short  s16x8;
typedef __attribute__((ext_vector_type(4))) float  f32x4;

__device__ inline float bf2f(short s) {
  unsigned u = ((unsigned)(unsigned short)s) << 16;
  float f; __builtin_memcpy(&f, &u, 4); return f;
}
__device__ inline short f2bf(float f) {
  __hip_bfloat16 h = __float2bfloat16(f);
  short s; __builtin_memcpy(&s, &h, 2); return s;
}
__device__ inline float gelu_f(float v) {
  return 0.5f * v * (1.f + erff(v * 0.70710678118654752f));
}
__device__ inline f32x4 mfma_bf16(s16x8 a, s16x8 b, f32x4 c) {
  return __builtin_amdgcn_mfma_f32_16x16x32_bf16(
      __builtin_bit_cast(bf16x8, a), __builtin_bit_cast(bf16x8, b), c, 0, 0, 0);
}

// ---------------- prep: weights fp32->bf16, zero stats ----------------
__global__ __launch_bounds__(256) void prep_kernel(
    const float* __restrict__ fw, const float* __restrict__ w1,
    const float* __restrict__ w2, short* __restrict__ fwb,
    short* __restrict__ w1b, short* __restrict__ w2b, float* __restrict__ stats)
{
  int i = blockIdx.x * 256 + threadIdx.x;
  if (i < CO_ * CIN_) fwb[i] = f2bf(fw[i]);
  if (i < CO_ * CO_) { w1b[i] = f2bf(w1[i]); w2b[i] = f2bf(w2[i]); }
  if (i < 768) stats[i] = 0.f;
}

// ---------------- knn: 3 nearest neighbors + weights ----------------
__global__ __launch_bounds__(256) void knn_kernel(
    const float* __restrict__ xyz1, const float* __restrict__ xyz2,
    int* __restrict__ idxs, float* __restrict__ wts)
{
  __shared__ float4 pts[S_];   // 16KB: x,y,z,|p|^2
  const int b = blockIdx.y;
  const float* p2 = xyz2 + (size_t)b * S_ * 3;
  for (int j = threadIdx.x; j < S_; j += 256) {
    float x = p2[j*3+0], y = p2[j*3+1], z = p2[j*3+2];
    pts[j] = make_float4(x, y, z, x*x + y*y + z*z);
  }
  __syncthreads();
  const int n = blockIdx.x * 256 + threadIdx.x;
  const float* q = xyz1 + ((size_t)b * N_ + n) * 3;
  const float qx = q[0], qy = q[1], qz = q[2];
  const float qq = qx*qx + qy*qy + qz*qz;
  float d0 = 3.4e38f, d1 = 3.4e38f, d2 = 3.4e38f;
  int   i0 = 0, i1 = 0, i2 = 0;
  #pragma unroll 4
  for (int j = 0; j < S_; ++j) {
    float4 p = pts[j];   // wave-uniform address -> LDS broadcast
    float d = qq + p.w - 2.f * (qx*p.x + qy*p.y + qz*p.z);
    bool c2 = d < d2;
    d2 = c2 ? d : d2;  i2 = c2 ? j : i2;
    bool c1 = d2 < d1;
    float td = d1; int ti = i1;
    d1 = c1 ? d2 : d1; i1 = c1 ? i2 : i1;
    d2 = c1 ? td : d2; i2 = c1 ? ti : i2;
    bool c0 = d1 < d0;
    td = d0; ti = i0;
    d0 = c0 ? d1 : d0; i0 = c0 ? i1 : i0;
    d1 = c0 ? td : d1; i1 = c0 ? ti : i1;
  }
  // reference: d = sqrt(max(sq,1e-12)); r = 1/(d+1e-8); w = r/sum(r)
  float r0 = 1.f / (sqrtf(fmaxf(d0, 1e-12f)) + 1e-8f);
  float r1 = 1.f / (sqrtf(fmaxf(d1, 1e-12f)) + 1e-8f);
  float r2 = 1.f / (sqrtf(fmaxf(d2, 1e-12f)) + 1e-8f);
  float rs = 1.f / (r0 + r1 + r2);
  size_t o = ((size_t)b * N_ + n) * 3;
  idxs[o+0] = i0; idxs[o+1] = i1; idxs[o+2] = i2;
  wts [o+0] = r0*rs; wts[o+1] = r1*rs; wts[o+2] = r2*rs;
}

// ---------------- interp + concat -> new_points bf16 [ROWS][384] ----------------
__global__ __launch_bounds__(384) void interp_kernel(
    const float* __restrict__ points1, const float* __restrict__ points2,
    const int* __restrict__ idxs, const float* __restrict__ wts,
    short* __restrict__ np_out)
{
  const int rid = blockIdx.x;          // 0..65535
  const int b = rid >> 12;             // rid / 4096
  const int t = threadIdx.x;
  short* out = np_out + (size_t)rid * CIN_;
  if (t < C1_) {
    out[t] = f2bf(points1[(size_t)rid * C1_ + t]);
  } else {
    const int c = t - C1_;
    const int* id = idxs + (size_t)rid * 3;
    const float* w = wts + (size_t)rid * 3;
    const float* p2 = points2 + (size_t)b * S_ * C2_;
    float v = w[0] * p2[(size_t)id[0] * C2_ + c]
            + w[1] * p2[(size_t)id[1] * C2_ + c]
            + w[2] * p2[(size_t)id[2] * C2_ + c];
    out[t] = f2bf(v);
  }
}

// ---------------- GEMM (M x K) @ (128 x K)^T -> raw bf16, + BN stats ----------------
// block = 4 waves; wave owns 32 rows x 128 cols. A,W fragments direct global->VGPR.
template<int K>
__global__ __launch_bounds__(256) void gemm_bn_kernel(
    const short* __restrict__ A, const short* __restrict__ W,
    short* __restrict__ Raw, float* __restrict__ gsum, float* __restrict__ gsq)
{
  const int tid  = threadIdx.x;
  const int wave = tid >> 6, lane = tid & 63;
  const int l16  = lane & 15, lk = lane >> 4;
  const int row0 = blockIdx.x * 128 + wave * 32;

  __shared__ float ssum[CO_], ssq[CO_];
  if (tid < CO_) { ssum[tid] = 0.f; ssq[tid] = 0.f; }

  f32x4 acc[2][8];
  #pragma unroll
  for (int m = 0; m < 2; ++m)
    #pragma unroll
    for (int n = 0; n < 8; ++n) acc[m][n] = f32x4{0.f, 0.f, 0.f, 0.f};

  const short* a0 = A + (size_t)(row0 + l16) * K + lk * 8;
  const short* a1 = a0 + (size_t)16 * K;
  const short* w0 = W + (size_t)l16 * K + lk * 8;

  #pragma unroll 4
  for (int kk = 0; kk < K; kk += 32) {
    s16x8 af0 = *(const s16x8*)(a0 + kk);
    s16x8 af1 = *(const s16x8*)(a1 + kk);
    s16x8 wf[8];
    #pragma unroll
    for (int n = 0; n < 8; ++n)
      wf[n] = *(const s16x8*)(w0 + (size_t)n * 16 * K + kk);
    #pragma unroll
    for (int n = 0; n < 8; ++n) {
      acc[0][n] = mfma_bf16(af0, wf[n], acc[0][n]);
      acc[1][n] = mfma_bf16(af1, wf[n], acc[1][n]);
    }
  }
  __syncthreads();   // ssum/ssq init visible

  // per-channel partial sums: C/D layout col=lane&15, row=(lane>>4)*4+r
  #pragma unroll
  for (int n = 0; n < 8; ++n) {
    float s = 0.f, q = 0.f;
    #pragma unroll
    for (int m = 0; m < 2; ++m)
      #pragma unroll
      for (int r = 0; r < 4; ++r) { float v = acc[m][n][r]; s += v; q += v*v; }
    s += __shfl_xor(s, 16); q += __shfl_xor(q, 16);
    s += __shfl_xor(s, 32); q += __shfl_xor(q, 32);
    if (lane < 16) {
      atomicAdd(&ssum[n*16 + l16], s);
      atomicAdd(&ssq [n*16 + l16], q);
    }
  }

  #pragma unroll
  for (int m = 0; m < 2; ++m)
    #pragma unroll
    for (int n = 0; n < 8; ++n)
      #pragma unroll
      for (int r = 0; r < 4; ++r) {
        int row = row0 + m*16 + lk*4 + r;
        Raw[(size_t)row * CO_ + n*16 + l16] = f2bf(acc[m][n][r]);
      }

  __syncthreads();
  if (tid < CO_)      atomicAdd(&gsum[tid],        ssum[tid]);
  else                atomicAdd(&gsq [tid - CO_],  ssq [tid - CO_]);
}

// ---------------- BN + GELU (+ optional residual, fp32 out) ----------------
template<bool FINAL>
__global__ __launch_bounds__(256) void bn_act_kernel(
    const short* __restrict__ raw, const float* __restrict__ gsum,
    const float* __restrict__ gsq, const float* __restrict__ gamma,
    const float* __restrict__ beta, const short* __restrict__ xres,
    void* __restrict__ outp)
{
  __shared__ float ssc[CO_], ssh[CO_];
  const int tid = threadIdx.x;
  if (tid < CO_) {
    const float inv = 1.f / (float)ROWS;
    float mean = gsum[tid] * inv;
    float var  = gsq[tid] * inv - mean * mean;
    float sc   = gamma[tid] * rsqrtf(var + 1e-5f);
    ssc[tid] = sc;
    ssh[tid] = beta[tid] - mean * sc;
  }
  __syncthreads();
  const int gid = blockIdx.x * 256 + tid;
  float sc[8], sh[8];
  const int cpos = (gid & 15) * 8;   // stride (2048*256) % 16 == 0 -> constant per thread
  #pragma unroll
  for (int j = 0; j < 8; ++j) { sc[j] = ssc[cpos + j]; sh[j] = ssh[cpos + j]; }
  const int NCHUNK = ROWS * CO_ / 8;
  const int stride = gridDim.x * 256;
  for (int ch = gid; ch < NCHUNK; ch += stride) {
    s16x8 rv = ((const s16x8*)raw)[ch];
    if (!FINAL) {
      s16x8 ov;
      #pragma unroll
      for (int j = 0; j < 8; ++j)
        ov[j] = f2bf(gelu_f(bf2f(rv[j]) * sc[j] + sh[j]));
      ((s16x8*)outp)[ch] = ov;
    } else {
      s16x8 xv = ((const s16x8*)xres)[ch];
      f32x4 o0, o1;
      #pragma unroll
      for (int j = 0; j < 4; ++j)
        o0[j] = gelu_f(bf2f(rv[j]) * sc[j] + sh[j] + bf2f(xv[j]));
      #pragma unroll
      for (int j = 0; j < 4; ++j)
        o1[j] = gelu_f(bf2f(rv[j+4]) * sc[j+4] + sh[j+4] + bf2f(xv[j+4]));
      ((f32x4*)outp)[2*(size_t)ch]     = o0;
      ((f32x4*)outp)[2*(size_t)ch + 1] = o1;
    }
  }
}

// ---------------- launch ----------------
extern "C" void kernel_launch(void* const* d_in, const int* in_sizes, int n_in,
                              void* d_out, int out_size, void* d_ws, size_t ws_size,
                              hipStream_t stream) {
  const float* xyz1    = (const float*)d_in[0];
  const float* xyz2    = (const float*)d_in[1];
  const float* points1 = (const float*)d_in[2];
  const float* points2 = (const float*)d_in[3];
  const float* fuse_w  = (const float*)d_in[4];
  const float* fuse_g  = (const float*)d_in[6];
  const float* fuse_bt = (const float*)d_in[7];
  const float* w1      = (const float*)d_in[8];
  const float* g1      = (const float*)d_in[10];
  const float* bt1     = (const float*)d_in[11];
  const float* w2      = (const float*)d_in[12];
  const float* g2      = (const float*)d_in[14];
  const float* bt2     = (const float*)d_in[15];

  char* ws = (char*)d_ws;
  // layout (bytes): np 0..48MB (x reuses 0..16MB, h reuses 16..32MB after gemm1)
  short* np_b  = (short*)(ws);
  short* x_b   = (short*)(ws);              // reuse after gemm1 consumed np
  short* h_b   = (short*)(ws + 16777216);
  short* raw   = (short*)(ws + 50331648);
  short* wf_b  = (short*)(ws + 67108864);
  short* w1_b  = (short*)(ws + 67207168);
  short* w2_b  = (short*)(ws + 67239936);
  int*   idxs  = (int*)  (ws + 67272704);
  float* wts   = (float*)(ws + 68059136);
  float* stats = (float*)(ws + 68845568);   // 6 x 128 floats
  float *sum1 = stats,       *sq1 = stats + 128;
  float *sum2 = stats + 256, *sq2 = stats + 384;
  float *sum3 = stats + 512, *sq3 = stats + 640;

  prep_kernel<<<192, 256, 0, stream>>>(fuse_w, w1, w2, wf_b, w1_b, w2_b, stats);
  knn_kernel<<<dim3(N_/256, B_), 256, 0, stream>>>(xyz1, xyz2, idxs, wts);
  interp_kernel<<<ROWS, 384, 0, stream>>>(points1, points2, idxs, wts, np_b);

  gemm_bn_kernel<CIN_><<<ROWS/128, 256, 0, stream>>>(np_b, wf_b, raw, sum1, sq1);
  bn_act_kernel<false><<<2048, 256, 0, stream>>>(raw, sum1, sq1, fuse_g, fuse_bt, nullptr, x_b);

  gemm_bn_kernel<CO_><<<ROWS/128, 256, 0, stream>>>(x_b, w1_b, raw, sum2, sq2);
  bn_act_kernel<false><<<2048, 256, 0, stream>>>(raw, sum2, sq2, g1, bt1, nullptr, h_b);

  gemm_bn_kernel<CO_><<<ROWS/128, 256, 0, stream>>>(h_b, w2_b, raw, sum3, sq3);
  bn_act_kernel<true><<<2048, 256, 0, stream>>>(raw, sum3, sq3, g2, bt2, x_b, d_out);
}

// Round 2
// 311.533 us; speedup vs baseline: 1.1512x; 1.1512x over previous
//
#include <hip/hip_runtime.h>
#include <hip/hip_bf16.h>
#include <math.h>

#define B_   16
#define N_   4096
#define S_   1024
#define C1_  128
#define C2_  256
#define CIN_ 384
#define CO_  128
#define ROWS (B_ * N_)   // 65536

typedef __attribute__((ext_vector_type(8))) __bf16 bf16x8;
typedef __attribute__((ext_vector_type(8))) short  s16x8;
typedef __attribute__((ext_vector_type(4))) short  s16x4;
typedef __attribute__((ext_vector_type(4))) float  f32x4;

__device__ inline float bf2f(short s) {
  unsigned u = ((unsigned)(unsigned short)s) << 16;
  float f; __builtin_memcpy(&f, &u, 4); return f;
}
__device__ inline short f2bf(float f) {
  __hip_bfloat16 h = __float2bfloat16(f);
  short s; __builtin_memcpy(&s, &h, 2); return s;
}
__device__ inline float gelu_f(float v) {
  return 0.5f * v * (1.f + erff(v * 0.70710678118654752f));
}
__device__ inline f32x4 mfma_bf16(s16x8 a, s16x8 b, f32x4 c) {
  return __builtin_amdgcn_mfma_f32_16x16x32_bf16(
      __builtin_bit_cast(bf16x8, a), __builtin_bit_cast(bf16x8, b), c, 0, 0, 0);
}
__device__ inline s16x8 pack8(f32x4 a, f32x4 b) {
  s16x8 r;
  #pragma unroll
  for (int j = 0; j < 4; ++j) { r[j] = f2bf(a[j]); r[j+4] = f2bf(b[j]); }
  return r;
}

// ---------------- prep: weights fp32->bf16, zero stats ----------------
__global__ __launch_bounds__(256) void prep_kernel(
    const float* __restrict__ fw, const float* __restrict__ w1,
    const float* __restrict__ w2, short* __restrict__ fwb,
    short* __restrict__ w1b, short* __restrict__ w2b, float* __restrict__ stats)
{
  int i = blockIdx.x * 256 + threadIdx.x;
  if (i < CO_ * CIN_) fwb[i] = f2bf(fw[i]);
  if (i < CO_ * CO_) { w1b[i] = f2bf(w1[i]); w2b[i] = f2bf(w2[i]); }
  if (i < 768) stats[i] = 0.f;
}

// ---------------- knn: 8 lanes per query, partitioned scan + shfl merge ----------------
__global__ __launch_bounds__(256) void knn_kernel(
    const float* __restrict__ xyz1, const float* __restrict__ xyz2,
    int* __restrict__ idxs, float* __restrict__ wts)
{
  __shared__ float4 pts[S_];   // 16KB: x,y,z,|p|^2
  const int b = blockIdx.y;
  const float* pp = xyz2 + (size_t)b * S_ * 3;
  for (int j = threadIdx.x; j < S_; j += 256) {
    float x = pp[j*3+0], y = pp[j*3+1], z = pp[j*3+2];
    pts[j] = make_float4(x, y, z, x*x + y*y + z*z);
  }
  __syncthreads();
  const int t   = blockIdx.x * 256 + threadIdx.x;
  const int n   = t >> 3;          // query id within batch
  const int sub = t & 7;
  const float* q = xyz1 + ((size_t)b * N_ + n) * 3;
  const float qx = q[0], qy = q[1], qz = q[2];
  const float qq = qx*qx + qy*qy + qz*qz;

  float d0 = 3.4e38f, d1 = 3.4e38f, d2 = 3.4e38f;
  int   i0 = 0, i1 = 0, i2 = 0;
  auto ins = [&](float d, int i) {
    bool c2 = d < d2;  d2 = c2 ? d : d2;  i2 = c2 ? i : i2;
    bool c1 = d2 < d1; float td = d1; int ti = i1;
    d1 = c1 ? d2 : d1; i1 = c1 ? i2 : i1;
    d2 = c1 ? td : d2; i2 = c1 ? ti : i2;
    bool c0 = d1 < d0; td = d0; ti = i0;
    d0 = c0 ? d1 : d0; i0 = c0 ? i1 : i0;
    d1 = c0 ? td : d1; i1 = c0 ? ti : i1;
  };
  // scan candidates j = it*8 + sub (qq added after selection; constant shift)
  #pragma unroll 4
  for (int it = 0; it < S_ / 8; ++it) {
    int j = it * 8 + sub;
    float4 p = pts[j];
    float dot = fmaf(qz, p.z, fmaf(qy, p.y, qx * p.x));
    float d = fmaf(-2.f, dot, p.w);
    ins(d, j);
  }
  // merge top-3 across the 8 sub-lanes
  #pragma unroll
  for (int delta = 1; delta < 8; delta <<= 1) {
    float e0 = __shfl_xor(d0, delta), e1 = __shfl_xor(d1, delta), e2 = __shfl_xor(d2, delta);
    int   j0 = __shfl_xor(i0, delta), j1 = __shfl_xor(i1, delta), j2 = __shfl_xor(i2, delta);
    ins(e0, j0); ins(e1, j1); ins(e2, j2);
  }
  if (sub == 0) {
    float r0 = 1.f / (sqrtf(fmaxf(d0 + qq, 1e-12f)) + 1e-8f);
    float r1 = 1.f / (sqrtf(fmaxf(d1 + qq, 1e-12f)) + 1e-8f);
    float r2 = 1.f / (sqrtf(fmaxf(d2 + qq, 1e-12f)) + 1e-8f);
    float rs = 1.f / (r0 + r1 + r2);
    size_t o = ((size_t)b * N_ + n) * 3;
    idxs[o+0] = i0; idxs[o+1] = i1; idxs[o+2] = i2;
    wts [o+0] = r0*rs; wts[o+1] = r1*rs; wts[o+2] = r2*rs;
  }
}

// ---------------- shared GEMM epilogue: BN stats + bf16x4 coalesced store ----------------
// swapped-operand layout: acc[m][n], channel = m*16 + lk*4 + r, data row = row0 + n*16 + l16
__device__ inline void epilogue_store_stats(
    f32x4 (&acc)[8][2], int row0, int l16, int lk,
    short* __restrict__ Raw, float* __restrict__ ssum, float* __restrict__ ssq)
{
  #pragma unroll
  for (int m = 0; m < 8; ++m) {
    f32x4 sv = acc[m][0] + acc[m][1];
    f32x4 qv = acc[m][0]*acc[m][0] + acc[m][1]*acc[m][1];
    #pragma unroll
    for (int r = 0; r < 4; ++r) {
      float s = sv[r], q = qv[r];
      s += __shfl_xor(s, 1); q += __shfl_xor(q, 1);
      s += __shfl_xor(s, 2); q += __shfl_xor(q, 2);
      s += __shfl_xor(s, 4); q += __shfl_xor(q, 4);
      s += __shfl_xor(s, 8); q += __shfl_xor(q, 8);
      if (l16 == 0) {
        int c = m*16 + lk*4 + r;
        atomicAdd(&ssum[c], s); atomicAdd(&ssq[c], q);
      }
    }
    #pragma unroll
    for (int nf = 0; nf < 2; ++nf) {
      s16x4 pv;
      #pragma unroll
      for (int r = 0; r < 4; ++r) pv[r] = f2bf(acc[m][nf][r]);
      *(s16x4*)(Raw + (size_t)(row0 + nf*16 + l16) * CO_ + m*16 + lk*4) = pv;
    }
  }
}

// ---------------- gemm1 fused: on-the-fly concat(points1, interp) -> raw + stats ----------------
__global__ __launch_bounds__(256) void gemm1_fused_kernel(
    const float* __restrict__ p1, const float* __restrict__ p2,
    const int* __restrict__ idxs, const float* __restrict__ wts,
    const short* __restrict__ W, short* __restrict__ Raw,
    float* __restrict__ gsum, float* __restrict__ gsq)
{
  const int tid  = threadIdx.x;
  const int wave = tid >> 6, lane = tid & 63;
  const int l16  = lane & 15, lk = lane >> 4;
  const int row0 = blockIdx.x * 128 + wave * 32;

  __shared__ float ssum[CO_], ssq[CO_];
  if (tid < CO_) { ssum[tid] = 0.f; ssq[tid] = 0.f; }

  const int r0 = row0 + l16, r1 = r0 + 16;
  const int bb = row0 >> 12;
  // gather metadata (k-independent): 3 neighbor rows + weights per data row
  const float* p2b = p2 + (size_t)bb * S_ * C2_;
  const float* ga0 = p2b + (size_t)idxs[(size_t)r0*3+0] * C2_;
  const float* ga1 = p2b + (size_t)idxs[(size_t)r0*3+1] * C2_;
  const float* ga2 = p2b + (size_t)idxs[(size_t)r0*3+2] * C2_;
  const float  wa0 = wts[(size_t)r0*3+0], wa1 = wts[(size_t)r0*3+1], wa2 = wts[(size_t)r0*3+2];
  const float* gb0 = p2b + (size_t)idxs[(size_t)r1*3+0] * C2_;
  const float* gb1 = p2b + (size_t)idxs[(size_t)r1*3+1] * C2_;
  const float* gb2 = p2b + (size_t)idxs[(size_t)r1*3+2] * C2_;
  const float  wb0 = wts[(size_t)r1*3+0], wb1 = wts[(size_t)r1*3+1], wb2 = wts[(size_t)r1*3+2];

  f32x4 acc[8][2];
  #pragma unroll
  for (int m = 0; m < 8; ++m)
    #pragma unroll
    for (int nf = 0; nf < 2; ++nf) acc[m][nf] = f32x4{0.f,0.f,0.f,0.f};

  const short* wbase = W + (size_t)l16 * CIN_ + lk * 8;
  const float* p1r0  = p1 + (size_t)r0 * C1_ + lk * 8;
  const float* p1r1  = p1 + (size_t)r1 * C1_ + lk * 8;

  // region 1: k in [0,128)  — points1, fp32 -> bf16
  #pragma unroll
  for (int kk = 0; kk < 128; kk += 32) {
    s16x8 bf0 = pack8(*(const f32x4*)(p1r0 + kk), *(const f32x4*)(p1r0 + kk + 4));
    s16x8 bf1 = pack8(*(const f32x4*)(p1r1 + kk), *(const f32x4*)(p1r1 + kk + 4));
    #pragma unroll
    for (int m = 0; m < 8; ++m) {
      s16x8 wf = *(const s16x8*)(wbase + (size_t)m*16*CIN_ + kk);
      acc[m][0] = mfma_bf16(wf, bf0, acc[m][0]);
      acc[m][1] = mfma_bf16(wf, bf1, acc[m][1]);
    }
  }
  // region 2: k in [128,384) — 3-NN interpolation of points2, fp32 -> bf16
  #pragma unroll 4
  for (int kk2 = 0; kk2 < 256; kk2 += 32) {
    const int c = kk2 + lk * 8;
    f32x4 v0a = wa0 * *(const f32x4*)(ga0 + c)     + wa1 * *(const f32x4*)(ga1 + c)     + wa2 * *(const f32x4*)(ga2 + c);
    f32x4 v0b = wa0 * *(const f32x4*)(ga0 + c + 4) + wa1 * *(const f32x4*)(ga1 + c + 4) + wa2 * *(const f32x4*)(ga2 + c + 4);
    f32x4 v1a = wb0 * *(const f32x4*)(gb0 + c)     + wb1 * *(const f32x4*)(gb1 + c)     + wb2 * *(const f32x4*)(gb2 + c);
    f32x4 v1b = wb0 * *(const f32x4*)(gb0 + c + 4) + wb1 * *(const f32x4*)(gb1 + c + 4) + wb2 * *(const f32x4*)(gb2 + c + 4);
    s16x8 bf0 = pack8(v0a, v0b);
    s16x8 bf1 = pack8(v1a, v1b);
    #pragma unroll
    for (int m = 0; m < 8; ++m) {
      s16x8 wf = *(const s16x8*)(wbase + (size_t)m*16*CIN_ + 128 + kk2);
      acc[m][0] = mfma_bf16(wf, bf0, acc[m][0]);
      acc[m][1] = mfma_bf16(wf, bf1, acc[m][1]);
    }
  }

  __syncthreads();
  epilogue_store_stats(acc, row0, l16, lk, Raw, ssum, ssq);
  __syncthreads();
  if (tid < CO_)      atomicAdd(&gsum[tid],       ssum[tid]);
  else                atomicAdd(&gsq[tid - CO_],  ssq[tid - CO_]);
}

// ---------------- gemm layers 2/3: bf16 A row-major, swapped operands ----------------
template<int K>
__global__ __launch_bounds__(256) void gemm_bn_kernel(
    const short* __restrict__ A, const short* __restrict__ W,
    short* __restrict__ Raw, float* __restrict__ gsum, float* __restrict__ gsq)
{
  const int tid  = threadIdx.x;
  const int wave = tid >> 6, lane = tid & 63;
  const int l16  = lane & 15, lk = lane >> 4;
  const int row0 = blockIdx.x * 128 + wave * 32;

  __shared__ float ssum[CO_], ssq[CO_];
  if (tid < CO_) { ssum[tid] = 0.f; ssq[tid] = 0.f; }

  f32x4 acc[8][2];
  #pragma unroll
  for (int m = 0; m < 8; ++m)
    #pragma unroll
    for (int nf = 0; nf < 2; ++nf) acc[m][nf] = f32x4{0.f,0.f,0.f,0.f};

  const short* a0    = A + (size_t)(row0 + l16) * K + lk * 8;
  const short* a1    = a0 + (size_t)16 * K;
  const short* wbase = W + (size_t)l16 * K + lk * 8;

  #pragma unroll 4
  for (int kk = 0; kk < K; kk += 32) {
    s16x8 bf0 = *(const s16x8*)(a0 + kk);
    s16x8 bf1 = *(const s16x8*)(a1 + kk);
    #pragma unroll
    for (int m = 0; m < 8; ++m) {
      s16x8 wf = *(const s16x8*)(wbase + (size_t)m*16*K + kk);
      acc[m][0] = mfma_bf16(wf, bf0, acc[m][0]);
      acc[m][1] = mfma_bf16(wf, bf1, acc[m][1]);
    }
  }

  __syncthreads();
  epilogue_store_stats(acc, row0, l16, lk, Raw, ssum, ssq);
  __syncthreads();
  if (tid < CO_)      atomicAdd(&gsum[tid],       ssum[tid]);
  else                atomicAdd(&gsq[tid - CO_],  ssq[tid - CO_]);
}

// ---------------- BN + GELU (+ optional residual, fp32 out) ----------------
template<bool FINAL>
__global__ __launch_bounds__(256) void bn_act_kernel(
    const short* __restrict__ raw, const float* __restrict__ gsum,
    const float* __restrict__ gsq, const float* __restrict__ gamma,
    const float* __restrict__ beta, const short* __restrict__ xres,
    void* __restrict__ outp)
{
  __shared__ float ssc[CO_], ssh[CO_];
  const int tid = threadIdx.x;
  if (tid < CO_) {
    const float inv = 1.f / (float)ROWS;
    float mean = gsum[tid] * inv;
    float var  = gsq[tid] * inv - mean * mean;
    float sc   = gamma[tid] * rsqrtf(var + 1e-5f);
    ssc[tid] = sc;
    ssh[tid] = beta[tid] - mean * sc;
  }
  __syncthreads();
  const int gid = blockIdx.x * 256 + tid;
  float sc[8], sh[8];
  const int cpos = (gid & 15) * 8;   // stride (2048*256) % 16 == 0 -> constant per thread
  #pragma unroll
  for (int j = 0; j < 8; ++j) { sc[j] = ssc[cpos + j]; sh[j] = ssh[cpos + j]; }
  const int NCHUNK = ROWS * CO_ / 8;
  const int stride = gridDim.x * 256;
  for (int ch = gid; ch < NCHUNK; ch += stride) {
    s16x8 rv = ((const s16x8*)raw)[ch];
    if (!FINAL) {
      s16x8 ov;
      #pragma unroll
      for (int j = 0; j < 8; ++j)
        ov[j] = f2bf(gelu_f(bf2f(rv[j]) * sc[j] + sh[j]));
      ((s16x8*)outp)[ch] = ov;
    } else {
      s16x8 xv = ((const s16x8*)xres)[ch];
      f32x4 o0, o1;
      #pragma unroll
      for (int j = 0; j < 4; ++j)
        o0[j] = gelu_f(bf2f(rv[j]) * sc[j] + sh[j] + bf2f(xv[j]));
      #pragma unroll
      for (int j = 0; j < 4; ++j)
        o1[j] = gelu_f(bf2f(rv[j+4]) * sc[j+4] + sh[j+4] + bf2f(xv[j+4]));
      ((f32x4*)outp)[2*(size_t)ch]     = o0;
      ((f32x4*)outp)[2*(size_t)ch + 1] = o1;
    }
  }
}

// ---------------- launch ----------------
extern "C" void kernel_launch(void* const* d_in, const int* in_sizes, int n_in,
                              void* d_out, int out_size, void* d_ws, size_t ws_size,
                              hipStream_t stream) {
  const float* xyz1    = (const float*)d_in[0];
  const float* xyz2    = (const float*)d_in[1];
  const float* points1 = (const float*)d_in[2];
  const float* points2 = (const float*)d_in[3];
  const float* fuse_w  = (const float*)d_in[4];
  const float* fuse_g  = (const float*)d_in[6];
  const float* fuse_bt = (const float*)d_in[7];
  const float* w1      = (const float*)d_in[8];
  const float* g1      = (const float*)d_in[10];
  const float* bt1     = (const float*)d_in[11];
  const float* w2      = (const float*)d_in[12];
  const float* g2      = (const float*)d_in[14];
  const float* bt2     = (const float*)d_in[15];

  char* ws = (char*)d_ws;
  short* x_b   = (short*)(ws);                 // 16.8MB
  short* h_b   = (short*)(ws + 16777216);      // 16.8MB
  short* raw   = (short*)(ws + 33554432);      // 16.8MB
  short* wf_b  = (short*)(ws + 50331648);      // 96KB
  short* w1_b  = (short*)(ws + 50429952);      // 32KB
  short* w2_b  = (short*)(ws + 50462720);      // 32KB
  int*   idxs  = (int*)  (ws + 50495488);      // 768KB
  float* wts   = (float*)(ws + 51281920);      // 768KB
  float* stats = (float*)(ws + 52068352);      // 3KB
  float *sum1 = stats,       *sq1 = stats + 128;
  float *sum2 = stats + 256, *sq2 = stats + 384;
  float *sum3 = stats + 512, *sq3 = stats + 640;

  prep_kernel<<<192, 256, 0, stream>>>(fuse_w, w1, w2, wf_b, w1_b, w2_b, stats);
  knn_kernel<<<dim3(N_*8/256, B_), 256, 0, stream>>>(xyz1, xyz2, idxs, wts);

  gemm1_fused_kernel<<<ROWS/128, 256, 0, stream>>>(points1, points2, idxs, wts,
                                                   wf_b, raw, sum1, sq1);
  bn_act_kernel<false><<<2048, 256, 0, stream>>>(raw, sum1, sq1, fuse_g, fuse_bt, nullptr, x_b);

  gemm_bn_kernel<CO_><<<ROWS/128, 256, 0, stream>>>(x_b, w1_b, raw, sum2, sq2);
  bn_act_kernel<false><<<2048, 256, 0, stream>>>(raw, sum2, sq2, g1, bt1, nullptr, h_b);

  gemm_bn_kernel<CO_><<<ROWS/128, 256, 0, stream>>>(h_b, w2_b, raw, sum3, sq3);
  bn_act_kernel<true><<<2048, 256, 0, stream>>>(raw, sum3, sq3, g2, bt2, x_b, d_out);
}